// Round 16
// baseline (161.491 us; speedup 1.0000x reference)
//
#include <hip/hip_runtime.h>
#include <cmath>

#define NB 32
#define C1N 64
#define DIM 256
#define NHEAD 8
#define SEQL 784
#define NA 1605632      /* NB*SEQL*C1N */
#define SEQN 6422528    /* NB*SEQL*DIM */
#define KSEL 803u
#define QK2S (0.17677669529663687f * 1.4426950408889634f)  /* (1/sqrt(32)) * log2(e) */
#define THR2 11.541560f              /* 8 * log2(e) */
#define PECOEF (-0.03597789207803197f) /* -ln(10000)/256 */

#define AS1 __attribute__((address_space(1)))
#define AS3 __attribute__((address_space(3)))

typedef __attribute__((ext_vector_type(8))) short bf16x8;
typedef __attribute__((ext_vector_type(4))) float f32x4;

__device__ __forceinline__ unsigned short f2b(float f) {
  unsigned u = __float_as_uint(f);
  unsigned r = u + 0x7fffu + ((u >> 16) & 1u);
  return (unsigned short)(r >> 16);
}

__device__ __forceinline__ unsigned cvt_pk_bf16(float lo, float hi) {
  unsigned r;
  asm("v_cvt_pk_bf16_f32 %0, %1, %2" : "=v"(r) : "v"(lo), "v"(hi));
  return r;
}

// 256-wide suffix scan in LDS (256 participating threads)
__device__ __forceinline__ void scan256_suffix(unsigned* ss, int t) {
  #pragma unroll
  for (int off = 1; off < 256; off <<= 1) {
    unsigned v = (t + off < 256) ? ss[t + off] : 0u;
    __syncthreads();
    ss[t] += v;
    __syncthreads();
  }
}

// ---------------- zero hists/sel + cast in_proj weights (fused) ----------------
__global__ __launch_bounds__(256) void k_init(const float* __restrict__ ipw,
                                              unsigned short* __restrict__ wbuf,
                                              unsigned* __restrict__ z) {
  int i = blockIdx.x * 256 + threadIdx.x;
  if (i < 66080) z[i] = 0u;
  wbuf[i] = f2b(ipw[i]);   // grid covers exactly 196608
}

// ---- conv + relu + radix stage-A (top-byte) LDS-privatized histogram ----
__global__ __launch_bounds__(256) void k_conv(const float* __restrict__ x,
                                              const float* __restrict__ cw,
                                              float* __restrict__ vbuf,
                                              unsigned* __restrict__ hist8a) {
  __shared__ __align__(16) float ximg[1296];   // 36x36 zero-padded image
  __shared__ float wlds[5184];                 // [tap 0..80][channel 0..63]
  __shared__ unsigned lh[256];
  int tid = threadIdx.x;
  int b = blockIdx.x / 7, sblk = blockIdx.x % 7;
  lh[tid] = 0u;
  for (int e = tid; e < 1296; e += 256) ximg[e] = 0.f;
  for (int e = tid; e < 5184; e += 256) {
    int c = e / 81, t = e - c * 81;
    wlds[t * 64 + c] = cw[e];
  }
  __syncthreads();
  const float* xb = x + b * 784;
  for (int e = tid; e < 784; e += 256) {
    int row = e / 28, col = e - row * 28;
    ximg[(row + 4) * 36 + col + 4] = xb[e];
  }
  __syncthreads();
  int wv = tid >> 6, lane = tid & 63;
  for (int it = 0; it < 7; ++it) {
    int grp = sblk * 28 + it * 4 + wv;     // 0..195
    int hr = grp / 7, wc0 = (grp % 7) * 4;
    float a0 = 0.f, a1 = 0.f, a2 = 0.f, a3 = 0.f;
    #pragma unroll
    for (int dy = 0; dy < 9; ++dy) {
      const float4* xr4 = (const float4*)&ximg[(hr + dy) * 36 + wc0];
      float4 xa = xr4[0], xbq = xr4[1], xc = xr4[2];
      float xr[12] = {xa.x, xa.y, xa.z, xa.w, xbq.x, xbq.y, xbq.z, xbq.w,
                      xc.x, xc.y, xc.z, xc.w};
      #pragma unroll
      for (int dx = 0; dx < 9; ++dx) {
        float w = wlds[(dy * 9 + dx) * 64 + lane];
        a0 = fmaf(xr[dx + 0], w, a0);
        a1 = fmaf(xr[dx + 1], w, a1);
        a2 = fmaf(xr[dx + 2], w, a2);
        a3 = fmaf(xr[dx + 3], w, a3);
      }
    }
    a0 = fmaxf(a0, 0.f); a1 = fmaxf(a1, 0.f);
    a2 = fmaxf(a2, 0.f); a3 = fmaxf(a3, 0.f);
    size_t base = ((size_t)(b * 784 + hr * 28 + wc0)) * 64 + lane;
    vbuf[base +   0] = a0;
    vbuf[base +  64] = a1;
    vbuf[base + 128] = a2;
    vbuf[base + 192] = a3;
    if (a0 > 0.f) atomicAdd(&lh[__float_as_uint(a0) >> 24], 1u);
    if (a1 > 0.f) atomicAdd(&lh[__float_as_uint(a1) >> 24], 1u);
    if (a2 > 0.f) atomicAdd(&lh[__float_as_uint(a2) >> 24], 1u);
    if (a3 > 0.f) atomicAdd(&lh[__float_as_uint(a3) >> 24], 1u);
  }
  __syncthreads();
  if (lh[tid] > 0u) atomicAdd(&hist8a[tid], lh[tid]);
}

// ---- radix stage B: re-derive stage-A bucket per block, hist next byte ----
__global__ __launch_bounds__(256) void k_h8b(const float* __restrict__ vbuf,
                                             const unsigned* __restrict__ hist8a,
                                             unsigned* __restrict__ hist8b) {
  __shared__ unsigned ss[256];
  __shared__ unsigned lh[256];
  __shared__ unsigned bkey;
  int t = threadIdx.x;
  ss[t] = hist8a[t];
  lh[t] = 0u;
  __syncthreads();
  scan256_suffix(ss, t);
  if (ss[0] < KSEL) return;                 // uniform fallback: threshold 0
  unsigned S = ss[t], ab = (t < 255) ? ss[t + 1] : 0u;
  if (S >= KSEL && ab < KSEL) bkey = (unsigned)t;
  __syncthreads();
  unsigned key = bkey;
  const float4* v4 = (const float4*)vbuf;
  int n4 = NA / 4;
  for (int i = blockIdx.x * 256 + t; i < n4; i += gridDim.x * 256) {
    float4 v = v4[i];
    float vv[4] = {v.x, v.y, v.z, v.w};
    #pragma unroll
    for (int j = 0; j < 4; ++j) {
      if (vv[j] > 0.0f) {
        unsigned bits = __float_as_uint(vv[j]);
        if ((bits >> 24) == key) atomicAdd(&lh[(bits >> 16) & 0xFFu], 1u);
      }
    }
  }
  __syncthreads();
  if (lh[t] > 0u) atomicAdd(&hist8b[t], lh[t]);
}

// ---- radix stage C: re-derive A+B buckets per block, hist low 16 bits ----
__global__ __launch_bounds__(256) void k_h16(const float* __restrict__ vbuf,
                                             const unsigned* __restrict__ hist8a,
                                             const unsigned* __restrict__ hist8b,
                                             unsigned* __restrict__ hist16) {
  __shared__ unsigned ss[256];
  __shared__ unsigned bk0, bk1, brem;
  int t = threadIdx.x;
  ss[t] = hist8a[t];
  __syncthreads();
  scan256_suffix(ss, t);
  if (ss[0] < KSEL) return;
  unsigned S = ss[t], ab = (t < 255) ? ss[t + 1] : 0u;
  if (S >= KSEL && ab < KSEL) { bk0 = (unsigned)t; brem = KSEL - ab; }
  __syncthreads();
  unsigned key0 = bk0, rem1 = brem;
  __syncthreads();
  ss[t] = hist8b[t];
  __syncthreads();
  scan256_suffix(ss, t);
  S = ss[t]; ab = (t < 255) ? ss[t + 1] : 0u;
  if (S >= rem1 && ab < rem1) bk1 = (unsigned)t;
  __syncthreads();
  unsigned key16 = (key0 << 8) | bk1;
  const float4* v4 = (const float4*)vbuf;
  int n4 = NA / 4;
  for (int i = blockIdx.x * 256 + t; i < n4; i += gridDim.x * 256) {
    float4 v = v4[i];
    float vv[4] = {v.x, v.y, v.z, v.w};
    #pragma unroll
    for (int j = 0; j < 4; ++j) {
      if (vv[j] > 0.0f) {
        unsigned bits = __float_as_uint(vv[j]);
        if ((bits >> 16) == key16) atomicAdd(&hist16[bits & 0xFFFFu], 1u);
      }
    }
  }
}

// ---- radix final: re-derive A+B, scan 65536 bins, write threshold sel[3] ----
__global__ __launch_bounds__(1024) void k_scan16(const unsigned* __restrict__ hist8a,
                                                 const unsigned* __restrict__ hist8b,
                                                 const unsigned* __restrict__ hist16,
                                                 unsigned* __restrict__ sel) {
  __shared__ unsigned ss[1024];
  __shared__ unsigned bk0, bk1, brem, brem2;
  int t = threadIdx.x;
  if (t < 256) ss[t] = hist8a[t];
  __syncthreads();
  for (int off = 1; off < 256; off <<= 1) {
    unsigned v = 0u;
    if (t < 256) v = (t + off < 256) ? ss[t + off] : 0u;
    __syncthreads();
    if (t < 256) ss[t] += v;
    __syncthreads();
  }
  if (ss[0] < KSEL) { if (t == 0) sel[3] = 0u; return; }
  if (t < 256) {
    unsigned S = ss[t], ab = (t < 255) ? ss[t + 1] : 0u;
    if (S >= KSEL && ab < KSEL) { bk0 = (unsigned)t; brem = KSEL - ab; }
  }
  __syncthreads();
  unsigned key0 = bk0, rem1 = brem;
  if (t < 256) ss[t] = hist8b[t];
  __syncthreads();
  for (int off = 1; off < 256; off <<= 1) {
    unsigned v = 0u;
    if (t < 256) v = (t + off < 256) ? ss[t + off] : 0u;
    __syncthreads();
    if (t < 256) ss[t] += v;
    __syncthreads();
  }
  if (t < 256) {
    unsigned S = ss[t], ab = (t < 255) ? ss[t + 1] : 0u;
    if (S >= rem1 && ab < rem1) { bk1 = (unsigned)t; brem2 = rem1 - ab; }
  }
  __syncthreads();
  unsigned key16 = (key0 << 8) | bk1;
  unsigned rem2 = brem2;
  unsigned sum = 0;
  for (int i = 0; i < 64; ++i) sum += hist16[t * 64 + i];
  ss[t] = sum;
  __syncthreads();
  for (int off = 1; off < 1024; off <<= 1) {
    unsigned v = (t + off < 1024) ? ss[t + off] : 0u;
    __syncthreads();
    ss[t] += v;
    __syncthreads();
  }
  unsigned S = ss[t];
  unsigned above = (t < 1023) ? ss[t + 1] : 0u;
  if (S >= rem2 && above < rem2) {
    unsigned cum = above;
    for (int bb = t * 64 + 63; bb >= t * 64; --bb) {
      unsigned hb = hist16[bb];
      cum += hb;
      if (cum >= rem2) {
        sel[3] = (key16 << 16) | (unsigned)bb;
        break;
      }
    }
  }
}

// ---------------- top-2 select + sparse softmax + embed + pos-enc (seq in bf16) ----
__global__ __launch_bounds__(256) void k_select(const float* __restrict__ vbuf,
                                                const unsigned* __restrict__ sel,
                                                const float* __restrict__ ce,
                                                unsigned short* __restrict__ seqb,
                                                float* __restrict__ out_sw,
                                                float* __restrict__ out_idx) {
  int wid = threadIdx.x >> 6;
  int lane = threadIdx.x & 63;
  int pos = blockIdx.x * 4 + wid;
  int hw = pos % 784;
  int hr = hw / 28;
  int wc = hw % 28;
  float thr = __uint_as_float(sel[3]);
  float a = vbuf[(size_t)pos * 64 + lane];
  float val = (a >= thr) ? a : 0.0f;
  unsigned long long nzm = __ballot(val > 0.0f);
  int count = __popcll(nzm);
  float v1 = val; int i1 = lane;
  #pragma unroll
  for (int off = 32; off > 0; off >>= 1) {
    float ov = __shfl_xor(v1, off);
    int oi = __shfl_xor(i1, off);
    if (ov > v1 || (ov == v1 && oi < i1)) { v1 = ov; i1 = oi; }
  }
  float vx = (lane == i1) ? -INFINITY : val;
  float v2 = vx; int i2 = lane;
  #pragma unroll
  for (int off = 32; off > 0; off >>= 1) {
    float ov = __shfl_xor(v2, off);
    int oi = __shfl_xor(i2, off);
    if (ov > v2 || (ov == v2 && oi < i2)) { v2 = ov; i2 = oi; }
  }
  float w1 = 0.0f, w2 = 0.0f;
  if (count >= 2) {
    float e = __expf(v2 - v1);
    float invd = 1.0f / (1.0f + e);
    w1 = invd; w2 = e * invd;
  } else if (count == 1) {
    w1 = 1.0f;
  }
  float wt = (lane == i1) ? w1 : ((lane == i2) ? w2 : 0.0f);
  out_sw[(size_t)pos * 64 + lane] = wt;
  if (lane < 2) out_idx[pos * 2 + lane] = (float)(lane == 0 ? i1 : i2);
  int d0 = lane * 4;
  float4 c1v = *(const float4*)(ce + (size_t)i1 * 256 + d0);
  float4 c2v = *(const float4*)(ce + (size_t)i2 * 256 + d0);
  float dv0 = __expf((float)d0 * PECOEF);
  float dv2 = __expf((float)(d0 + 2) * PECOEF);
  float ox = w1 * c1v.x + w2 * c2v.x + __sinf((float)hr * dv0);
  float oy = w1 * c1v.y + w2 * c2v.y + __cosf((float)wc * dv0);
  float oz = w1 * c1v.z + w2 * c2v.z + __sinf((float)hr * dv2);
  float ow = w1 * c1v.w + w2 * c2v.w + __cosf((float)wc * dv2);
  ushort4 ob = make_ushort4(f2b(ox), f2b(oy), f2b(oz), f2b(ow));
  *(ushort4*)(seqb + (size_t)pos * 256 + d0) = ob;
}

// ---- LDS-staged MFMA bf16 GEMM: C = A[M][K] @ W[N][K]^T + bias. Q cols pre-scaled
// by QK2S. V-blocks (n0>=512) store DIRECTLY to Vt (transposed + k-permuted). ----
__global__ __launch_bounds__(256) void k_gemm_lds(const unsigned short* __restrict__ A,
                                                  const unsigned short* __restrict__ W,
                                                  const float* __restrict__ bias,
                                                  unsigned short* __restrict__ C,
                                                  unsigned short* __restrict__ Vt,
                                                  int M, int N, int K) {
  __shared__ __align__(16) unsigned short As[8192];   // [128][64]
  __shared__ __align__(16) unsigned short Bs[8192];
  int tid = threadIdx.x;
  int lane = tid & 63, wid = tid >> 6;
  int q = lane & 15, g = lane >> 4;
  int m0 = blockIdx.y * 128, n0 = blockIdx.x * 128;
  int lrow = lane >> 3, s = lane & 7;
  const unsigned short* aSrc = A + (size_t)(m0 + wid * 8 + lrow) * K + (s ^ lrow) * 8;
  const unsigned short* bSrc = W + (size_t)(n0 + wid * 8 + lrow) * K + (s ^ lrow) * 8;
  int dstW = wid * 512;
  int mloc = (wid >> 1) * 64, nloc = (wid & 1) * 64;
  int q7 = q & 7;
  f32x4 acc[4][4];
  #pragma unroll
  for (int i = 0; i < 4; ++i)
    #pragma unroll
    for (int j = 0; j < 4; ++j) acc[i][j] = (f32x4){0.f, 0.f, 0.f, 0.f};
  for (int k0 = 0; k0 < K; k0 += 64) {
    #pragma unroll
    for (int i = 0; i < 4; ++i) {
      __builtin_amdgcn_global_load_lds((const AS1 void*)(aSrc + (size_t)i * 32 * K + k0),
                                       (AS3 void*)(&As[i * 2048 + dstW]), 16, 0, 0);
      __builtin_amdgcn_global_load_lds((const AS1 void*)(bSrc + (size_t)i * 32 * K + k0),
                                       (AS3 void*)(&Bs[i * 2048 + dstW]), 16, 0, 0);
    }
    __syncthreads();
    #pragma unroll
    for (int kk = 0; kk < 2; ++kk) {
      bf16x8 af[4], bf[4];
      #pragma unroll
      for (int i = 0; i < 4; ++i)
        af[i] = *(const bf16x8*)&As[(mloc + i * 16 + q) * 64 + (((kk * 4 + g) ^ q7) * 8)];
      #pragma unroll
      for (int j = 0; j < 4; ++j)
        bf[j] = *(const bf16x8*)&Bs[(nloc + j * 16 + q) * 64 + (((kk * 4 + g) ^ q7) * 8)];
      __builtin_amdgcn_s_setprio(1);
      #pragma unroll
      for (int i = 0; i < 4; ++i)
        #pragma unroll
        for (int j = 0; j < 4; ++j)
          acc[i][j] = __builtin_amdgcn_mfma_f32_16x16x32_bf16(af[i], bf[j], acc[i][j], 0, 0, 0);
      __builtin_amdgcn_s_setprio(0);
    }
    __syncthreads();
  }
  if (n0 < 512) {   // Q/K blocks -> qkv layout
    #pragma unroll
    for (int j = 0; j < 4; ++j) {
      int col = n0 + nloc + j * 16 + q;
      float bj = bias[col];
      float qs = (col < 256) ? QK2S : 1.0f;
      #pragma unroll
      for (int i = 0; i < 4; ++i) {
        #pragma unroll
        for (int r = 0; r < 4; ++r) {
          int row = m0 + mloc + i * 16 + g * 4 + r;
          C[(size_t)row * N + col] = f2b((acc[i][j][r] + bj) * qs);
        }
      }
    }
  } else {          // V blocks -> transposed + permuted Vt[(b*8+nh)*32+d][800]
    #pragma unroll
    for (int j = 0; j < 4; ++j) {
      int colV = n0 + nloc + j * 16 + q;
      float bj = bias[colV];
      int dtot = colV - 512;
      size_t vrow = ((size_t)(dtot >> 5) * 32 + (dtot & 31)) * 800;  // + b*8*32*800
      #pragma unroll
      for (int i = 0; i < 4; ++i) {
        int rowbase = m0 + mloc + i * 16;        // 16-aligned; whole group same b
        int b = rowbase / 784;
        int t16 = rowbase - b * 784;             // multiple of 16
        int pos = ((t16 >> 5) << 5) + ((t16 >> 4) & 1) * 4 + g * 8;
        uint2 o;
        o.x = cvt_pk_bf16(acc[i][j][0] + bj, acc[i][j][1] + bj);
        o.y = cvt_pk_bf16(acc[i][j][2] + bj, acc[i][j][3] + bj);
        *(uint2*)(Vt + (size_t)b * 8 * 32 * 800 + vrow + pos) = o;
      }
    }
  }
}

// ---- MFMA flash attention: 4 waves/block share (b,head); 3-buffer LDS pipeline,
// counted vmcnt(1). l computed on matrix pipe via all-ones A-fragment MFMA;
// defer-max rescale (THR2). [3x-green variant: R9/R10/R11 benches] ----
__global__ __launch_bounds__(256) void k_attn(const unsigned short* __restrict__ qkv,
                                              const unsigned short* __restrict__ Vt,
                                              unsigned short* __restrict__ ctx) {
  __shared__ __align__(16) unsigned short Kt[3][1024];   // [buf][32 keys x 32 dims]
  __shared__ __align__(16) unsigned short Vti[3][1024];  // [buf][32 dims x 32 kpos]
  int wid = threadIdx.x >> 6;
  int lane = threadIdx.x & 63;
  int blk = blockIdx.x;                       // 3328 = 8 XCDs * 416
  int wrk = (blk & 7) * 416 + (blk >> 3);
  int bh = wrk / 13;
  int qb = (wrk - bh * 13) * 4 + wid;         // 0..51
  int b = bh >> 3, nh = bh & 7;
  int q = lane & 15, g = lane >> 4;
  bool active = (qb < 49);
  const f32x4 zero4 = {0.f, 0.f, 0.f, 0.f};
  const short one_bf = (short)0x3F80;         // bf16 1.0
  const bf16x8 ones8 = {one_bf, one_bf, one_bf, one_bf,
                        one_bf, one_bf, one_bf, one_bf};

  int qrow = b * 784 + (active ? qb * 16 + q : q);
  bf16x8 qf = *(const bf16x8*)(qkv + (size_t)qrow * 768 + nh * 32 + g * 8);
  asm volatile("s_waitcnt vmcnt(0)" ::: "memory");   // qf resident; vmcnt baseline 0

  const unsigned short* kbase = qkv + (size_t)b * 784 * 768 + 256 + nh * 32;
  const unsigned short* vbase = Vt + (size_t)bh * 32 * 800;

  int rit = ((wid & 1) << 4) + (lane >> 2);
  int sG = (lane & 3) ^ ((rit + (rit >> 2)) & 3);
  bool isK = (wid < 2);
  int ldsoff = ((wid & 1) << 4) * 32;
  const unsigned short* sp = isK ? (kbase + (size_t)rit * 768 + sG * 8)
                                 : (vbase + (size_t)rit * 800 + sG * 8);
  const int sstride = isK ? (32 * 768) : 32;
  unsigned short* ldsb = (isK ? &Kt[0][0] : &Vti[0][0]) + ldsoff;

  int slotr = ((g ^ ((q + (q >> 2)) & 3)) << 3);
  int rowA = q * 32 + slotr;
  int rowB = (16 + q) * 32 + slotr;

  f32x4 acc0 = zero4, acc1 = zero4, accS = zero4;
  float m = -INFINITY;

#define STAGE(BUFO) {                                                          \
    __builtin_amdgcn_global_load_lds((const AS1 void*)sp,                      \
                                     (AS3 void*)(ldsb + (BUFO)), 16, 0, 0);    \
    sp += sstride; }

#define STEP(CUR, NXT) {                                                       \
    asm volatile("s_waitcnt vmcnt(1)" ::: "memory");                           \
    __builtin_amdgcn_s_barrier();                                              \
    asm volatile("" ::: "memory");                                             \
    STAGE(NXT);                                                                \
    bf16x8 kA = *(const bf16x8*)&Kt[0][(CUR) + rowA];                          \
    bf16x8 kB = *(const bf16x8*)&Kt[0][(CUR) + rowB];                          \
    bf16x8 va = *(const bf16x8*)&Vti[0][(CUR) + rowA];                         \
    bf16x8 vb = *(const bf16x8*)&Vti[0][(CUR) + rowB];                         \
    __builtin_amdgcn_s_setprio(1);                                             \
    f32x4 s0 = __builtin_amdgcn_mfma_f32_16x16x32_bf16(kA, qf, zero4, 0, 0, 0);\
    f32x4 s1 = __builtin_amdgcn_mfma_f32_16x16x32_bf16(kB, qf, zero4, 0, 0, 0);\
    __builtin_amdgcn_s_setprio(0);                                             \
    float t1 = fmaxf(fmaxf(s0[0], s0[1]), s0[2]);                              \
    float t2 = fmaxf(fmaxf(s0[3], s1[0]), s1[1]);                              \
    float t3 = fmaxf(fmaxf(s1[2], s1[3]), t1);                                 \
    float pl = fmaxf(t2, t3);                                                  \
    if (!__all(pl <= m + THR2)) {                                              \
      float pm = fmaxf(pl, __shfl_xor(pl, 16));                                \
      pm = fmaxf(pm, __shfl_xor(pm, 32));                                      \
      float mnew = fmaxf(m, pm);                                               \
      float sc = __builtin_amdgcn_exp2f(m - mnew);                             \
      acc0 *= sc; acc1 *= sc; accS *= sc;                                      \
      m = mnew;                                                                \
    }                                                                          \
    float p0[4], p1[4];                                                        \
    _Pragma("unroll")                                                          \
    for (int r = 0; r < 4; ++r) {                                              \
      p0[r] = __builtin_amdgcn_exp2f(s0[r] - m);                               \
      p1[r] = __builtin_amdgcn_exp2f(s1[r] - m);                               \
    }                                                                          \
    union { unsigned u[4]; bf16x8 v; } pu;                                     \
    pu.u[0] = cvt_pk_bf16(p0[0], p0[1]);                                       \
    pu.u[1] = cvt_pk_bf16(p0[2], p0[3]);                                       \
    pu.u[2] = cvt_pk_bf16(p1[0], p1[1]);                                       \
    pu.u[3] = cvt_pk_bf16(p1[2], p1[3]);                                       \
    __builtin_amdgcn_s_setprio(1);                                             \
    acc0 = __builtin_amdgcn_mfma_f32_16x16x32_bf16(va, pu.v, acc0, 0, 0, 0);   \
    acc1 = __builtin_amdgcn_mfma_f32_16x16x32_bf16(vb, pu.v, acc1, 0, 0, 0);   \
    accS = __builtin_amdgcn_mfma_f32_16x16x32_bf16(ones8, pu.v, accS, 0, 0, 0);\
    __builtin_amdgcn_s_setprio(0);                                             \
  }

  STAGE(0);     // tile 0 -> buf0
  STAGE(1024);  // tile 1 -> buf1

  for (int t = 0; t < 8; ++t) {
    STEP(0, 2048);
    STEP(1024, 0);
    STEP(2048, 1024);
  }
  { // tail: tile 24 (keys 768..799) in buf0; nonexistent-key P slots are 0.
    asm volatile("s_waitcnt vmcnt(1)" ::: "memory");
    __builtin_amdgcn_s_barrier();
    asm volatile("" ::: "memory");
    bf16x8 kA = *(const bf16x8*)&Kt[0][rowA];
    bf16x8 va = *(const bf16x8*)&Vti[0][rowA];
    bf16x8 vb = *(const bf16x8*)&Vti[0][rowB];
    f32x4 s0 = __builtin_amdgcn_mfma_f32_16x16x32_bf16(kA, qf, zero4, 0, 0, 0);
    float pl = fmaxf(fmaxf(fmaxf(s0[0], s0[1]), s0[2]), s0[3]);
    if (!__all(pl <= m + THR2)) {
      float pm = fmaxf(pl, __shfl_xor(pl, 16));
      pm = fmaxf(pm, __shfl_xor(pm, 32));
      float mnew = fmaxf(m, pm);
      float sc = __builtin_amdgcn_exp2f(m - mnew);
      acc0 *= sc; acc1 *= sc; accS *= sc;
      m = mnew;
    }
    float p0[4];
    #pragma unroll
    for (int r = 0; r < 4; ++r) p0[r] = __builtin_amdgcn_exp2f(s0[r] - m);
    union { unsigned u[4]; bf16x8 v; } pu;
    pu.u[0] = cvt_pk_bf16(p0[0], p0[1]);
    pu.u[1] = cvt_pk_bf16(p0[2], p0[3]);
    pu.u[2] = 0u;
    pu.u[3] = 0u;
    acc0 = __builtin_amdgcn_mfma_f32_16x16x32_bf16(va, pu.v, acc0, 0, 0, 0);
    acc1 = __builtin_amdgcn_mfma_f32_16x16x32_bf16(vb, pu.v, acc1, 0, 0, 0);
    accS = __builtin_amdgcn_mfma_f32_16x16x32_bf16(ones8, pu.v, accS, 0, 0, 0);
  }
#undef STEP
#undef STAGE
  float linv = 1.f / accS[0];
  if (active) {
    unsigned short* cp = ctx + (size_t)(b * 784 + qb * 16 + q) * 256 + nh * 32;
    ushort4 oA = make_ushort4(f2b(acc0[0] * linv), f2b(acc0[1] * linv),
                              f2b(acc0[2] * linv), f2b(acc0[3] * linv));
    ushort4 oB = make_ushort4(f2b(acc1[0] * linv), f2b(acc1[1] * linv),
                              f2b(acc1[2] * linv), f2b(acc1[3] * linv));
    *(ushort4*)(cp + g * 4) = oA;
    *(ushort4*)(cp + 16 + g * 4) = oB;
  }
}

// ---- mean-pool ctx (bf16 -> f32 partials): out-proj is deferred to a tiny GEMV ----
__global__ __launch_bounds__(256) void k_poolctx(const unsigned short* __restrict__ ctx,
                                                 float* __restrict__ part) {
  int b = blockIdx.x >> 3, sseg = blockIdx.x & 7;
  int d = threadIdx.x;
  const unsigned short* base = ctx + ((size_t)b * 784 + sseg * 98) * 256 + d;
  float acc = 0.f;
  for (int t = 0; t < 98; ++t)
    acc += __uint_as_float((unsigned)base[(size_t)t * 256] << 16);
  part[(size_t)blockIdx.x * 256 + d] = acc;
}

// ---- pooled[b] = mean_ctx[b] @ opw^T + opb  (f32, exact out-proj of the mean) ----
__global__ __launch_bounds__(256) void k_pgemv(const float* __restrict__ part,
                                               const float* __restrict__ opw,
                                               const float* __restrict__ opb,
                                               float* __restrict__ out) {
  __shared__ float mc[256];
  int b = blockIdx.x, d = threadIdx.x;
  float s = 0.f;
  #pragma unroll
  for (int i = 0; i < 8; ++i) s += part[(size_t)(b * 8 + i) * 256 + d];
  mc[d] = s * (1.0f / 784.0f);
  __syncthreads();
  float acc = opb[d];
  const float4* wr = (const float4*)(opw + (size_t)d * 256);
  #pragma unroll 8
  for (int j = 0; j < 64; ++j) {
    float4 w = wr[j];
    float4 m4 = *(const float4*)&mc[j * 4];
    acc += m4.x * w.x + m4.y * w.y + m4.z * w.z + m4.w * w.w;
  }
  out[b * 256 + d] = acc;
}

extern "C" void kernel_launch(void* const* d_in, const int* in_sizes, int n_in,
                              void* d_out, int out_size, void* d_ws, size_t ws_size,
                              hipStream_t stream) {
  (void)in_sizes; (void)n_in; (void)out_size; (void)ws_size;
  const float* x   = (const float*)d_in[0];
  const float* cw  = (const float*)d_in[1];
  const float* ce  = (const float*)d_in[2];
  const float* ipw = (const float*)d_in[3];
  const float* ipb = (const float*)d_in[4];
  const float* opw = (const float*)d_in[5];
  const float* opb = (const float*)d_in[6];

  float* out = (float*)d_out;
  float* pooled  = out;
  float* out_sw  = out + 8192;
  float* out_idx = out + 8192 + NA;

  float* ws = (float*)d_ws;
  float* vbuf = ws;                                   // NA f32
  unsigned* hist16 = (unsigned*)(ws + NA);            // 65536
  unsigned* hist8a = hist16 + 65536;                  // 256
  unsigned* hist8b = hist8a + 256;                    // 256
  unsigned* sel    = hist8b + 256;                    // 16
  unsigned short* seqb = (unsigned short*)(ws + NA + 66080);  // SEQN bf16 (later: ctx)
  unsigned short* qkvb = seqb + SEQN;                 // 3*SEQN bf16 (V region unused)
  unsigned short* Vt   = qkvb + 3 * (size_t)SEQN;     // 256*32*800 bf16
  unsigned short* wbuf = Vt + 256 * 32 * 800;         // 196608 bf16 (in_proj only)
  float* part = (float*)(wbuf + 262144);              // 65536 f32

  k_init<<<768, 256, 0, stream>>>(ipw, wbuf, hist16);
  k_conv<<<224, 256, 0, stream>>>(x, cw, vbuf, hist8a);
  k_h8b<<<1024, 256, 0, stream>>>(vbuf, hist8a, hist8b);
  k_h16<<<1024, 256, 0, stream>>>(vbuf, hist8a, hist8b, hist16);
  k_scan16<<<1, 1024, 0, stream>>>(hist8a, hist8b, hist16, sel);
  k_select<<<25088 / 4, 256, 0, stream>>>(vbuf, sel, ce, seqb, out_sw, out_idx);
  {
    dim3 gq(768 / 128, 25088 / 128);
    k_gemm_lds<<<gq, 256, 0, stream>>>(seqb, wbuf, ipb, qkvb, Vt, 25088, 768, 256);
  }
  k_attn<<<3328, 256, 0, stream>>>(qkvb, Vt, seqb /* ctx */);
  k_poolctx<<<256, 256, 0, stream>>>(seqb, part);
  k_pgemv<<<NB, 256, 0, stream>>>(part, opw, opb, pooled);
}